// Round 1
// baseline (661.021 us; speedup 1.0000x reference)
//
#include <hip/hip_runtime.h>

#define BS 8
#define LQ 900
#define NH 8
#define NL 4
#define NP 4
#define HD 32
#define ED 256
#define LEN_V 21760

static __device__ __forceinline__ unsigned short f2bf(float f) {
  union { float f; unsigned u; } x; x.f = f;
  unsigned r = x.u + 0x7fffu + ((x.u >> 16) & 1u);
  return (unsigned short)(r >> 16);
}
static __device__ __forceinline__ float bf2f(unsigned short s) {
  union { unsigned u; float f; } x; x.u = ((unsigned)s) << 16;
  return x.f;
}

// ---------------------------------------------------------------------------
// K1: v = value @ w_value + b_value, stored permuted [b][h][s][d] as bf16.
// Block: 256 threads, 32 rows x 256 cols. Thread: 8 rows (rg = t>>6) x 4 cols.
// ---------------------------------------------------------------------------
__global__ __launch_bounds__(256, 2) void vproj_kernel(
    const float* __restrict__ value, const float* __restrict__ w,
    const float* __restrict__ bias, unsigned short* __restrict__ vout) {
  const int t = threadIdx.x;
  const int row0 = blockIdx.x * 32;
  const int rg = t >> 6;         // 0..3 -> rows rg*8 .. rg*8+7
  const int c0 = (t & 63) << 2;  // column base (4 consecutive cols)
  __shared__ float a_lds[32][8];

  float4 acc[8];
#pragma unroll
  for (int r = 0; r < 8; r++) acc[r] = make_float4(0.f, 0.f, 0.f, 0.f);

  const int lr = t >> 3;   // staging row
  const int lk = t & 7;    // staging k
  for (int k0 = 0; k0 < 256; k0 += 8) {
    __syncthreads();
    a_lds[lr][lk] = value[(row0 + lr) * 256 + k0 + lk];
    __syncthreads();
    float4 wr[8];
#pragma unroll
    for (int k = 0; k < 8; k++)
      wr[k] = *(const float4*)&w[(k0 + k) * 256 + c0];
#pragma unroll
    for (int r = 0; r < 8; r++) {
      const float* ar = &a_lds[rg * 8 + r][0];
      float4 a0 = *(const float4*)&ar[0];
      float4 a1 = *(const float4*)&ar[4];
      float4 s = acc[r];
      s.x += a0.x*wr[0].x + a0.y*wr[1].x + a0.z*wr[2].x + a0.w*wr[3].x
           + a1.x*wr[4].x + a1.y*wr[5].x + a1.z*wr[6].x + a1.w*wr[7].x;
      s.y += a0.x*wr[0].y + a0.y*wr[1].y + a0.z*wr[2].y + a0.w*wr[3].y
           + a1.x*wr[4].y + a1.y*wr[5].y + a1.z*wr[6].y + a1.w*wr[7].y;
      s.z += a0.x*wr[0].z + a0.y*wr[1].z + a0.z*wr[2].z + a0.w*wr[3].z
           + a1.x*wr[4].z + a1.y*wr[5].z + a1.z*wr[6].z + a1.w*wr[7].z;
      s.w += a0.x*wr[0].w + a0.y*wr[1].w + a0.z*wr[2].w + a0.w*wr[3].w
           + a1.x*wr[4].w + a1.y*wr[5].w + a1.z*wr[6].w + a1.w*wr[7].w;
      acc[r] = s;
    }
  }

  const float4 bv = *(const float4*)&bias[c0];
  const int h = c0 >> 5;
  const int d0 = c0 & 31;
#pragma unroll
  for (int r = 0; r < 8; r++) {
    const int grow = row0 + rg * 8 + r;
    const int b = grow / LEN_V;
    const int s = grow - b * LEN_V;
    const int idx = ((b * NH + h) * LEN_V + s) * HD + d0;
    ushort4 pk;
    pk.x = f2bf(acc[r].x + bv.x);
    pk.y = f2bf(acc[r].y + bv.y);
    pk.z = f2bf(acc[r].z + bv.z);
    pk.w = f2bf(acc[r].w + bv.w);
    *(ushort4*)&vout[idx] = pk;
  }
}

// ---------------------------------------------------------------------------
// K2: fused offsets/attn projections + softmax + bilinear sampling + out proj.
// One block per (b, 4 queries), 256 threads.
// ---------------------------------------------------------------------------
__global__ __launch_bounds__(256, 2) void msda_kernel(
    const float* __restrict__ query, const float* __restrict__ refp,
    const unsigned short* __restrict__ vp,
    const float* __restrict__ w_off, const float* __restrict__ b_off,
    const float* __restrict__ w_attn, const float* __restrict__ b_attn,
    const float* __restrict__ w_out, const float* __restrict__ b_out,
    float* __restrict__ out) {
  const int t = threadIdx.x;
  const int b = blockIdx.x / (LQ / 4);
  const int q0 = (blockIdx.x % (LQ / 4)) * 4;

  __shared__ float q_lds[4][256];
  __shared__ float off_lds[4][256];
  __shared__ float aw_lds[4][128];
  __shared__ float res_lds[4][256];
  __shared__ float ref_lds[4][4][2];

#pragma unroll
  for (int qi = 0; qi < 4; qi++)
    q_lds[qi][t] = query[(b * LQ + q0 + qi) * 256 + t];
  if (t < 32) {
    const int qi = t >> 3, l = (t >> 1) & 3, xy = t & 1;
    ref_lds[qi][l][xy] = refp[((b * LQ + q0 + qi) * NL + l) * 2 + xy];
  }
  __syncthreads();

  // ---- sampling offsets: off[qi][t] ----
  {
    const float bo = b_off[t];
    float acc[4];
#pragma unroll
    for (int qi = 0; qi < 4; qi++) acc[qi] = bo;
    for (int c = 0; c < 256; c += 4) {
      const float w0 = w_off[(c + 0) * 256 + t];
      const float w1 = w_off[(c + 1) * 256 + t];
      const float w2 = w_off[(c + 2) * 256 + t];
      const float w3 = w_off[(c + 3) * 256 + t];
#pragma unroll
      for (int qi = 0; qi < 4; qi++) {
        const float4 qv = *(const float4*)&q_lds[qi][c];
        acc[qi] += qv.x * w0 + qv.y * w1 + qv.z * w2 + qv.w * w3;
      }
    }
#pragma unroll
    for (int qi = 0; qi < 4; qi++) off_lds[qi][t] = acc[qi];
  }

  // ---- attention logits: aw[qi][t], t < 128 ----
  if (t < 128) {
    const float ba = b_attn[t];
    float acc[4];
#pragma unroll
    for (int qi = 0; qi < 4; qi++) acc[qi] = ba;
    for (int c = 0; c < 256; c += 4) {
      const float w0 = w_attn[(c + 0) * 128 + t];
      const float w1 = w_attn[(c + 1) * 128 + t];
      const float w2 = w_attn[(c + 2) * 128 + t];
      const float w3 = w_attn[(c + 3) * 128 + t];
#pragma unroll
      for (int qi = 0; qi < 4; qi++) {
        const float4 qv = *(const float4*)&q_lds[qi][c];
        acc[qi] += qv.x * w0 + qv.y * w1 + qv.z * w2 + qv.w * w3;
      }
    }
#pragma unroll
    for (int qi = 0; qi < 4; qi++) aw_lds[qi][t] = acc[qi];
  }
  __syncthreads();

  // ---- softmax over the 16 (l,p) per (qi, h): 32 workers ----
  if (t < 32) {
    const int qi = t >> 3, h = t & 7;
    float* a = &aw_lds[qi][h * 16];
    float m = a[0];
#pragma unroll
    for (int i = 1; i < 16; i++) m = fmaxf(m, a[i]);
    float e[16];
    float ssum = 0.f;
#pragma unroll
    for (int i = 0; i < 16; i++) { e[i] = __expf(a[i] - m); ssum += e[i]; }
    const float inv = 1.f / ssum;
#pragma unroll
    for (int i = 0; i < 16; i++) a[i] = e[i] * inv;
  }
  __syncthreads();

  // ---- bilinear sampling: thread = (head h, dim d) ----
  const int h = t >> 5;
  const int d = t & 31;
  const int lvlW[4] = {128, 64, 32, 16};
  const int lvlH[4] = {128, 64, 32, 16};
  const int lvlS[4] = {0, 16384, 20480, 21504};
  const int vbase = (b * NH + h) * LEN_V * HD;
  float racc[4] = {0.f, 0.f, 0.f, 0.f};
#pragma unroll
  for (int l = 0; l < 4; l++) {
    const int W = lvlW[l], H = lvlH[l];
    const float Wf = (float)W, Hf = (float)H;
    const unsigned short* vl = vp + vbase + lvlS[l] * HD + d;
#pragma unroll
    for (int qi = 0; qi < 4; qi++) {
      const float refx = ref_lds[qi][l][0];
      const float refy = ref_lds[qi][l][1];
#pragma unroll
      for (int p = 0; p < 4; p++) {
        const float offx = off_lds[qi][h * 32 + l * 8 + p * 2 + 0];
        const float offy = off_lds[qi][h * 32 + l * 8 + p * 2 + 1];
        const float aw = aw_lds[qi][h * 16 + l * 4 + p];
        const float px = refx * Wf + offx - 0.5f;
        const float py = refy * Hf + offy - 0.5f;
        const float x0f = floorf(px), y0f = floorf(py);
        const float dx = px - x0f, dy = py - y0f;
        const int x0 = (int)x0f, y0 = (int)y0f;
        const int x1 = x0 + 1, y1 = y0 + 1;
        const float mx0 = (x0 >= 0 && x0 < W) ? 1.f : 0.f;
        const float mx1 = (x1 >= 0 && x1 < W) ? 1.f : 0.f;
        const float my0 = (y0 >= 0 && y0 < H) ? 1.f : 0.f;
        const float my1 = (y1 >= 0 && y1 < H) ? 1.f : 0.f;
        const int x0c = min(max(x0, 0), W - 1);
        const int x1c = min(max(x1, 0), W - 1);
        const int y0c = min(max(y0, 0), H - 1);
        const int y1c = min(max(y1, 0), H - 1);
        const float w00 = (1.f - dx) * (1.f - dy) * mx0 * my0;
        const float w10 = dx * (1.f - dy) * mx1 * my0;
        const float w01 = (1.f - dx) * dy * mx0 * my1;
        const float w11 = dx * dy * mx1 * my1;
        const float v00 = bf2f(vl[(y0c * W + x0c) * HD]);
        const float v10 = bf2f(vl[(y0c * W + x1c) * HD]);
        const float v01 = bf2f(vl[(y1c * W + x0c) * HD]);
        const float v11 = bf2f(vl[(y1c * W + x1c) * HD]);
        racc[qi] += aw * (w00 * v00 + w10 * v10 + w01 * v01 + w11 * v11);
      }
    }
  }
#pragma unroll
  for (int qi = 0; qi < 4; qi++) res_lds[qi][h * HD + d] = racc[qi];
  __syncthreads();

  // ---- output projection ----
  {
    const float bo = b_out[t];
    float acc[4];
#pragma unroll
    for (int qi = 0; qi < 4; qi++) acc[qi] = bo;
    for (int c = 0; c < 256; c += 4) {
      const float w0 = w_out[(c + 0) * 256 + t];
      const float w1 = w_out[(c + 1) * 256 + t];
      const float w2 = w_out[(c + 2) * 256 + t];
      const float w3 = w_out[(c + 3) * 256 + t];
#pragma unroll
      for (int qi = 0; qi < 4; qi++) {
        const float4 rv = *(const float4*)&res_lds[qi][c];
        acc[qi] += rv.x * w0 + rv.y * w1 + rv.z * w2 + rv.w * w3;
      }
    }
#pragma unroll
    for (int qi = 0; qi < 4; qi++)
      out[(b * LQ + q0 + qi) * 256 + t] = acc[qi];
  }
}

extern "C" void kernel_launch(void* const* d_in, const int* in_sizes, int n_in,
                              void* d_out, int out_size, void* d_ws, size_t ws_size,
                              hipStream_t stream) {
  (void)in_sizes; (void)n_in; (void)out_size; (void)ws_size;
  const float* query   = (const float*)d_in[0];
  const float* refp    = (const float*)d_in[1];
  const float* value   = (const float*)d_in[2];
  const float* w_value = (const float*)d_in[3];
  const float* b_value = (const float*)d_in[4];
  const float* w_off   = (const float*)d_in[5];
  const float* b_off   = (const float*)d_in[6];
  const float* w_attn  = (const float*)d_in[7];
  const float* b_attn  = (const float*)d_in[8];
  const float* w_out   = (const float*)d_in[9];
  const float* b_out   = (const float*)d_in[10];
  float* out = (float*)d_out;
  unsigned short* vp = (unsigned short*)d_ws;  // bf16 v, [b][h][s][d], 89 MB

  vproj_kernel<<<(BS * LEN_V) / 32, 256, 0, stream>>>(value, w_value, b_value, vp);
  msda_kernel<<<BS * (LQ / 4), 256, 0, stream>>>(query, refp, vp, w_off, b_off,
                                                 w_attn, b_attn, w_out, b_out, out);
}

// Round 2
// 435.103 us; speedup vs baseline: 1.5192x; 1.5192x over previous
//
#include <hip/hip_runtime.h>

#define BS 8
#define LQ 900
#define NH 8
#define NL 4
#define NP 4
#define HD 32
#define ED 256
#define LEN_V 21760

typedef __attribute__((ext_vector_type(8))) short bf16x8;
typedef __attribute__((ext_vector_type(4))) float f32x4;
typedef __attribute__((ext_vector_type(4))) float fv4;

static __device__ __forceinline__ unsigned short f2bf(float f) {
  union { float f; unsigned u; } x; x.f = f;
  unsigned r = x.u + 0x7fffu + ((x.u >> 16) & 1u);
  return (unsigned short)(r >> 16);
}
static __device__ __forceinline__ float bf2f(unsigned short s) {
  union { unsigned u; float f; } x; x.u = ((unsigned)s) << 16;
  return x.f;
}
static __device__ __forceinline__ unsigned pack2(float a, float b) {
  return (unsigned)f2bf(a) | ((unsigned)f2bf(b) << 16);
}

// ---------------------------------------------------------------------------
// K1: v = value @ w_value + b_value  (bf16 MFMA), output permuted [b][h][s][d]
// bf16. Block: 256 thr = 4 waves. Tile 64 rows x 256 cols; wave w covers all
// 64 rows x cols [w*64, w*64+64) as 4x4 frags of mfma_f32_16x16x32_bf16.
// LDS chunk = 16B = 8 k-contiguous bf16 (A-operand layout).
// ---------------------------------------------------------------------------
__global__ __launch_bounds__(256, 3) void vproj_kernel(
    const float* __restrict__ value, const float* __restrict__ w,
    const float* __restrict__ bias, unsigned short* __restrict__ vout) {
  const int t = threadIdx.x;
  const int row0 = blockIdx.x * 64;
  const int wv = t >> 6;          // wave id -> col block
  const int lane = t & 63;
  const int quad = lane >> 4;     // k-quad for fragments
  const int nn = lane & 15;

  // a_lds: chunks [quad(4)][row(64)]  -> A[row][k0+quad*8 .. +8]
  // b_lds: chunks [kseg(4)][n(256)]   -> B[k0+kseg*8 .. +8][n]
  __shared__ unsigned short a_lds[4 * 64 * 8];    // 4 KB
  __shared__ unsigned short b_lds[4 * 256 * 8];   // 16 KB

  f32x4 acc[4][4];
#pragma unroll
  for (int i = 0; i < 4; i++)
#pragma unroll
    for (int j = 0; j < 4; j++) acc[i][j] = (f32x4)(0.f);

  // staging roles
  const int arow = t >> 2;        // 0..63
  const int akseg = t & 3;        // 0..3
  const int bkseg = wv;           // wave-uniform k-seg for B staging
  const int bn = lane;            // n base (0..63), + 64*c

  for (int k0 = 0; k0 < 256; k0 += 32) {
    __syncthreads();
    // ---- stage A: 64 rows x 32 k fp32 -> bf16 chunks ----
    {
      const float* pa = &value[(row0 + arow) * 256 + k0 + akseg * 8];
      fv4 v0 = __builtin_nontemporal_load((const fv4*)pa);
      fv4 v1 = __builtin_nontemporal_load((const fv4*)(pa + 4));
      uint4 pk;
      pk.x = pack2(v0.x, v0.y);
      pk.y = pack2(v0.z, v0.w);
      pk.z = pack2(v1.x, v1.y);
      pk.w = pack2(v1.z, v1.w);
      *(uint4*)&a_lds[(akseg * 64 + arow) * 8] = pk;
    }
    // ---- stage B: 32 k x 256 n fp32 -> bf16 chunks (transpose in thread) ----
    {
      const float* pb = &w[(k0 + bkseg * 8) * 256 + bn];
#pragma unroll
      for (int c = 0; c < 4; c++) {
        float f[8];
#pragma unroll
        for (int j = 0; j < 8; j++) f[j] = pb[j * 256 + c * 64];
        uint4 pk;
        pk.x = pack2(f[0], f[1]);
        pk.y = pack2(f[2], f[3]);
        pk.z = pack2(f[4], f[5]);
        pk.w = pack2(f[6], f[7]);
        *(uint4*)&b_lds[(bkseg * 256 + c * 64 + bn) * 8] = pk;
      }
    }
    __syncthreads();

    // ---- fragments + MFMA ----
    bf16x8 af[4], bf[4];
#pragma unroll
    for (int rt = 0; rt < 4; rt++)
      af[rt] = *(const bf16x8*)&a_lds[(quad * 64 + rt * 16 + nn) * 8];
#pragma unroll
    for (int ct = 0; ct < 4; ct++)
      bf[ct] = *(const bf16x8*)&b_lds[(quad * 256 + wv * 64 + ct * 16 + nn) * 8];
#pragma unroll
    for (int rt = 0; rt < 4; rt++)
#pragma unroll
      for (int ct = 0; ct < 4; ct++)
        acc[rt][ct] = __builtin_amdgcn_mfma_f32_16x16x32_bf16(
            af[rt], bf[ct], acc[rt][ct], 0, 0, 0);
  }

  // ---- epilogue: C/D layout col=lane&15, row=quad*4+reg ----
#pragma unroll
  for (int ct = 0; ct < 4; ct++) {
    const int col = wv * 64 + ct * 16 + nn;
    const float bv = bias[col];
    const int h = col >> 5;
    const int d = col & 31;
#pragma unroll
    for (int rt = 0; rt < 4; rt++) {
      f32x4 f = acc[rt][ct];
#pragma unroll
      for (int reg = 0; reg < 4; reg++) {
        const int grow = row0 + rt * 16 + quad * 4 + reg;
        const int b = grow / LEN_V;
        const int s = grow - b * LEN_V;
        vout[((b * NH + h) * LEN_V + s) * HD + d] = f2bf(f[reg] + bv);
      }
    }
  }
}

// ---------------------------------------------------------------------------
// K2: fused offsets/attn projections + softmax + bilinear sampling + out proj.
// One block per (b, 4 queries), 256 threads.
// ---------------------------------------------------------------------------
__global__ __launch_bounds__(256, 4) void msda_kernel(
    const float* __restrict__ query, const float* __restrict__ refp,
    const unsigned short* __restrict__ vp,
    const float* __restrict__ w_off, const float* __restrict__ b_off,
    const float* __restrict__ w_attn, const float* __restrict__ b_attn,
    const float* __restrict__ w_out, const float* __restrict__ b_out,
    float* __restrict__ out) {
  const int t = threadIdx.x;
  const int b = blockIdx.x / (LQ / 4);
  const int q0 = (blockIdx.x % (LQ / 4)) * 4;

  __shared__ float q_lds[4][256];
  __shared__ float off_lds[4][256];
  __shared__ float aw_lds[4][128];
  __shared__ float res_lds[4][256];
  __shared__ float ref_lds[4][4][2];

#pragma unroll
  for (int qi = 0; qi < 4; qi++)
    q_lds[qi][t] = query[(b * LQ + q0 + qi) * 256 + t];
  if (t < 32) {
    const int qi = t >> 3, l = (t >> 1) & 3, xy = t & 1;
    ref_lds[qi][l][xy] = refp[((b * LQ + q0 + qi) * NL + l) * 2 + xy];
  }
  __syncthreads();

  // ---- sampling offsets: off[qi][t] ----
  {
    const float bo = b_off[t];
    float acc[4];
#pragma unroll
    for (int qi = 0; qi < 4; qi++) acc[qi] = bo;
    for (int c = 0; c < 256; c += 4) {
      const float w0 = w_off[(c + 0) * 256 + t];
      const float w1 = w_off[(c + 1) * 256 + t];
      const float w2 = w_off[(c + 2) * 256 + t];
      const float w3 = w_off[(c + 3) * 256 + t];
#pragma unroll
      for (int qi = 0; qi < 4; qi++) {
        const float4 qv = *(const float4*)&q_lds[qi][c];
        acc[qi] += qv.x * w0 + qv.y * w1 + qv.z * w2 + qv.w * w3;
      }
    }
#pragma unroll
    for (int qi = 0; qi < 4; qi++) off_lds[qi][t] = acc[qi];
  }

  // ---- attention logits: all 256 threads, 2 queries each ----
  {
    const int col = t & 127;
    const int qb = (t >> 7) * 2;
    const float ba = b_attn[col];
    float acc0 = ba, acc1 = ba;
    for (int c = 0; c < 256; c += 4) {
      const float w0 = w_attn[(c + 0) * 128 + col];
      const float w1 = w_attn[(c + 1) * 128 + col];
      const float w2 = w_attn[(c + 2) * 128 + col];
      const float w3 = w_attn[(c + 3) * 128 + col];
      const float4 qv0 = *(const float4*)&q_lds[qb][c];
      const float4 qv1 = *(const float4*)&q_lds[qb + 1][c];
      acc0 += qv0.x * w0 + qv0.y * w1 + qv0.z * w2 + qv0.w * w3;
      acc1 += qv1.x * w0 + qv1.y * w1 + qv1.z * w2 + qv1.w * w3;
    }
    aw_lds[qb][col] = acc0;
    aw_lds[qb + 1][col] = acc1;
  }
  __syncthreads();

  // ---- softmax over the 16 (l,p) per (qi, h): 32 workers ----
  if (t < 32) {
    const int qi = t >> 3, h = t & 7;
    float* a = &aw_lds[qi][h * 16];
    float m = a[0];
#pragma unroll
    for (int i = 1; i < 16; i++) m = fmaxf(m, a[i]);
    float e[16];
    float ssum = 0.f;
#pragma unroll
    for (int i = 0; i < 16; i++) { e[i] = __expf(a[i] - m); ssum += e[i]; }
    const float inv = 1.f / ssum;
#pragma unroll
    for (int i = 0; i < 16; i++) a[i] = e[i] * inv;
  }
  __syncthreads();

  // ---- bilinear sampling: thread = (head h, dim d) ----
  const int h = t >> 5;
  const int d = t & 31;
  const int lvlW[4] = {128, 64, 32, 16};
  const int lvlH[4] = {128, 64, 32, 16};
  const int lvlS[4] = {0, 16384, 20480, 21504};
  const int vbase = (b * NH + h) * LEN_V * HD;
  float racc[4] = {0.f, 0.f, 0.f, 0.f};
#pragma unroll
  for (int l = 0; l < 4; l++) {
    const int W = lvlW[l], H = lvlH[l];
    const float Wf = (float)W, Hf = (float)H;
    const unsigned short* vl = vp + vbase + lvlS[l] * HD + d;
#pragma unroll
    for (int qi = 0; qi < 4; qi++) {
      const float refx = ref_lds[qi][l][0];
      const float refy = ref_lds[qi][l][1];
#pragma unroll
      for (int p = 0; p < 4; p++) {
        const float offx = off_lds[qi][h * 32 + l * 8 + p * 2 + 0];
        const float offy = off_lds[qi][h * 32 + l * 8 + p * 2 + 1];
        const float aw = aw_lds[qi][h * 16 + l * 4 + p];
        const float px = refx * Wf + offx - 0.5f;
        const float py = refy * Hf + offy - 0.5f;
        const float x0f = floorf(px), y0f = floorf(py);
        const float dx = px - x0f, dy = py - y0f;
        const int x0 = (int)x0f, y0 = (int)y0f;
        const int x1 = x0 + 1, y1 = y0 + 1;
        const float mx0 = (x0 >= 0 && x0 < W) ? 1.f : 0.f;
        const float mx1 = (x1 >= 0 && x1 < W) ? 1.f : 0.f;
        const float my0 = (y0 >= 0 && y0 < H) ? 1.f : 0.f;
        const float my1 = (y1 >= 0 && y1 < H) ? 1.f : 0.f;
        const int x0c = min(max(x0, 0), W - 1);
        const int x1c = min(max(x1, 0), W - 1);
        const int y0c = min(max(y0, 0), H - 1);
        const int y1c = min(max(y1, 0), H - 1);
        const float w00 = (1.f - dx) * (1.f - dy) * mx0 * my0;
        const float w10 = dx * (1.f - dy) * mx1 * my0;
        const float w01 = (1.f - dx) * dy * mx0 * my1;
        const float w11 = dx * dy * mx1 * my1;
        const float v00 = bf2f(vl[(y0c * W + x0c) * HD]);
        const float v10 = bf2f(vl[(y0c * W + x1c) * HD]);
        const float v01 = bf2f(vl[(y1c * W + x0c) * HD]);
        const float v11 = bf2f(vl[(y1c * W + x1c) * HD]);
        racc[qi] += aw * (w00 * v00 + w10 * v10 + w01 * v01 + w11 * v11);
      }
    }
  }
#pragma unroll
  for (int qi = 0; qi < 4; qi++) res_lds[qi][h * HD + d] = racc[qi];
  __syncthreads();

  // ---- output projection ----
  {
    const float bo = b_out[t];
    float acc[4];
#pragma unroll
    for (int qi = 0; qi < 4; qi++) acc[qi] = bo;
    for (int c = 0; c < 256; c += 4) {
      const float w0 = w_out[(c + 0) * 256 + t];
      const float w1 = w_out[(c + 1) * 256 + t];
      const float w2 = w_out[(c + 2) * 256 + t];
      const float w3 = w_out[(c + 3) * 256 + t];
#pragma unroll
      for (int qi = 0; qi < 4; qi++) {
        const float4 rv = *(const float4*)&res_lds[qi][c];
        acc[qi] += rv.x * w0 + rv.y * w1 + rv.z * w2 + rv.w * w3;
      }
    }
#pragma unroll
    for (int qi = 0; qi < 4; qi++)
      out[(b * LQ + q0 + qi) * 256 + t] = acc[qi];
  }
}

extern "C" void kernel_launch(void* const* d_in, const int* in_sizes, int n_in,
                              void* d_out, int out_size, void* d_ws, size_t ws_size,
                              hipStream_t stream) {
  (void)in_sizes; (void)n_in; (void)out_size; (void)ws_size;
  const float* query   = (const float*)d_in[0];
  const float* refp    = (const float*)d_in[1];
  const float* value   = (const float*)d_in[2];
  const float* w_value = (const float*)d_in[3];
  const float* b_value = (const float*)d_in[4];
  const float* w_off   = (const float*)d_in[5];
  const float* b_off   = (const float*)d_in[6];
  const float* w_attn  = (const float*)d_in[7];
  const float* b_attn  = (const float*)d_in[8];
  const float* w_out   = (const float*)d_in[9];
  const float* b_out   = (const float*)d_in[10];
  float* out = (float*)d_out;
  unsigned short* vp = (unsigned short*)d_ws;  // bf16 v, [b][h][s][d], 89 MB

  vproj_kernel<<<(BS * LEN_V) / 64, 256, 0, stream>>>(value, w_value, b_value, vp);
  msda_kernel<<<BS * (LQ / 4), 256, 0, stream>>>(query, refp, vp, w_off, b_off,
                                                 w_attn, b_attn, w_out, b_out, out);
}